// Round 1
// baseline (1209.045 us; speedup 1.0000x reference)
//
#include <hip/hip_runtime.h>
#include <hip/hip_bf16.h>
#include <stdint.h>

// Problem constants (fixed by setup_inputs)
#define E_ 8
#define C_ 2048
#define H_ 2048
#define I_ 2816
#define N1_ (2 * I_)   // 5632

typedef __attribute__((ext_vector_type(8))) short bf16x8;
typedef __attribute__((ext_vector_type(4))) float f32x4;

__device__ __forceinline__ unsigned short f2bf(float f) {
  union { float f; unsigned int u; } v; v.f = f;
  unsigned int u = v.u;
  unsigned int r = (u + 0x7FFFu + ((u >> 16) & 1u)) >> 16;  // RNE
  return (unsigned short)r;
}

__device__ __forceinline__ void gload16(const void* g, const void* l) {
  __builtin_amdgcn_global_load_lds(
      (const __attribute__((address_space(1))) unsigned int*)g,
      (__attribute__((address_space(3))) unsigned int*)l, 16, 0, 0);
}

// ---------------- fp32 -> bf16 straight conversion (vectorized 8/thread) ----
__global__ __launch_bounds__(256) void cvt_bf16(const float* __restrict__ src,
                                                unsigned short* __restrict__ dst,
                                                int n8) {
  int idx = blockIdx.x * 256 + threadIdx.x;
  int stride = gridDim.x * 256;
  for (int i = idx; i < n8; i += stride) {
    const float4* s = (const float4*)(src + (size_t)i * 8);
    float4 a = s[0], b = s[1];
    uint4 o;
    o.x = (unsigned int)f2bf(a.x) | ((unsigned int)f2bf(a.y) << 16);
    o.y = (unsigned int)f2bf(a.z) | ((unsigned int)f2bf(a.w) << 16);
    o.z = (unsigned int)f2bf(b.x) | ((unsigned int)f2bf(b.y) << 16);
    o.w = (unsigned int)f2bf(b.z) | ((unsigned int)f2bf(b.w) << 16);
    *(uint4*)(dst + (size_t)i * 8) = o;
  }
}

// ---------------- fp32 [R][C] -> bf16 [C][R] per-expert transpose ----------
__global__ __launch_bounds__(256) void transpose_cvt(const float* __restrict__ src,
                                                     unsigned short* __restrict__ dst,
                                                     int R, int C) {
  int tilesC = C >> 6, tilesR = R >> 6;
  int tiles = tilesR * tilesC;
  int bid = blockIdx.x;
  int e = bid / tiles;
  int r2 = bid % tiles;
  int tr = r2 / tilesC, tc = r2 % tilesC;
  const float* s = src + (size_t)e * R * C;
  unsigned short* d = dst + (size_t)e * R * C;
  int r0 = tr << 6, c0 = tc << 6;

  __shared__ unsigned short lds[64 * 72];
  int t = threadIdx.x;
  int tx = t & 15, ty = t >> 4;
#pragma unroll
  for (int p = 0; p < 4; ++p) {
    int row = p * 16 + ty;
    float4 v = *(const float4*)(s + (size_t)(r0 + row) * C + c0 + tx * 4);
    int colb = tx * 4;
    lds[(colb + 0) * 72 + row] = f2bf(v.x);
    lds[(colb + 1) * 72 + row] = f2bf(v.y);
    lds[(colb + 2) * 72 + row] = f2bf(v.z);
    lds[(colb + 3) * 72 + row] = f2bf(v.w);
  }
  __syncthreads();
#pragma unroll
  for (int it = 0; it < 2; ++it) {
    int q = it * 256 + t;
    int nl = q >> 3, hc = q & 7;
    uint4 vv = *(const uint4*)(&lds[nl * 72 + hc * 8]);
    *(uint4*)(d + (size_t)(c0 + nl) * R + r0 + hc * 8) = vv;
  }
}

// ---------------- GEMM1: act = silu(A@Bg) * (A@Bu), all bf16 ---------------
// A: [E][C][H] (k-major). BT: [E][2I][H] (n-major = transposed weights).
// act: [E][C][I] bf16.
// Tile 128x128x64, 4 waves (2x2), per-wave 64x64 per matrix.
__global__ __launch_bounds__(256) void gemm1_glu(const unsigned short* __restrict__ A,
                                                 const unsigned short* __restrict__ BT,
                                                 unsigned short* __restrict__ act) {
  const int MT = C_ / 128;   // 16
  const int NT = I_ / 128;   // 22
  int bid = blockIdx.x;
  int e = bid / (MT * NT);
  int r2 = bid % (MT * NT);
  int m0 = (r2 % MT) << 7;
  int n0 = (r2 / MT) << 7;

  const unsigned short* Ae = A + (size_t)e * C_ * H_;
  const unsigned short* Ge = BT + (size_t)e * N1_ * H_ + (size_t)n0 * H_;
  const unsigned short* Ue = Ge + (size_t)I_ * H_;
  unsigned short* Ce = act + (size_t)e * C_ * I_;

  __shared__ unsigned short lds[3 * 8192];  // A | Bg | Bu tiles, 16 KB each

  int t = threadIdx.x, lane = t & 63, wave = t >> 6;
  int wr = (wave >> 1) << 6;   // wave row offset in tile
  int wc = (wave & 1) << 6;    // wave col offset in tile

  f32x4 accg[4][4] = {};
  f32x4 accu[4][4] = {};

  int prow[4], pco[4], ldso[4];
#pragma unroll
  for (int it = 0; it < 4; ++it) {
    int p = it * 256 + t;
    prow[it] = p >> 3;
    int pc = p & 7;
    pco[it] = ((pc ^ (prow[it] & 7)) << 3);   // XOR-swizzled source chunk
    ldso[it] = (it * 256 + wave * 64) << 4;   // wave-uniform LDS byte offset
  }

  for (int k0 = 0; k0 < H_; k0 += 64) {
    __syncthreads();
#pragma unroll
    for (int it = 0; it < 4; ++it) {
      gload16(Ae + (size_t)(m0 + prow[it]) * H_ + k0 + pco[it],
              (const char*)lds + ldso[it]);
      gload16(Ge + (size_t)prow[it] * H_ + k0 + pco[it],
              (const char*)lds + 16384 + ldso[it]);
      gload16(Ue + (size_t)prow[it] * H_ + k0 + pco[it],
              (const char*)lds + 32768 + ldso[it]);
    }
    __syncthreads();
#pragma unroll
    for (int kk = 0; kk < 2; ++kk) {
      bf16x8 af[4], gf[4], uf[4];
      int kg = (kk << 2) + (lane >> 4);
#pragma unroll
      for (int mi = 0; mi < 4; ++mi) {
        int row = wr + (mi << 4) + (lane & 15);
        int x = kg ^ (row & 7);
        af[mi] = *(const bf16x8*)((const char*)lds + row * 128 + (x << 4));
      }
#pragma unroll
      for (int ni = 0; ni < 4; ++ni) {
        int row = wc + (ni << 4) + (lane & 15);
        int x = kg ^ (row & 7);
        gf[ni] = *(const bf16x8*)((const char*)lds + 16384 + row * 128 + (x << 4));
        uf[ni] = *(const bf16x8*)((const char*)lds + 32768 + row * 128 + (x << 4));
      }
#pragma unroll
      for (int mi = 0; mi < 4; ++mi)
#pragma unroll
        for (int ni = 0; ni < 4; ++ni) {
          accg[mi][ni] = __builtin_amdgcn_mfma_f32_16x16x32_bf16(af[mi], gf[ni], accg[mi][ni], 0, 0, 0);
          accu[mi][ni] = __builtin_amdgcn_mfma_f32_16x16x32_bf16(af[mi], uf[ni], accu[mi][ni], 0, 0, 0);
        }
    }
  }

  // Epilogue: act = silu(g) * u  (C/D layout: col=lane&15, row=(lane>>4)*4+reg)
  int rbase = m0 + wr + ((lane >> 4) << 2);
  int cbase = n0 + wc + (lane & 15);
#pragma unroll
  for (int mi = 0; mi < 4; ++mi)
#pragma unroll
    for (int ni = 0; ni < 4; ++ni)
#pragma unroll
      for (int r = 0; r < 4; ++r) {
        int row = rbase + (mi << 4) + r;
        int col = cbase + (ni << 4);
        float g = accg[mi][ni][r];
        float u = accu[mi][ni][r];
        float s = g / (1.0f + __expf(-g));
        Ce[(size_t)row * I_ + col] = f2bf(s * u);
      }
}

// ---------------- GEMM2: out = act @ down, fp32 output ---------------------
// A: [E][C][I] bf16. BT: [E][H][I] bf16 (n-major). Out: [E][C][H] fp32.
__global__ __launch_bounds__(256) void gemm2_down(const unsigned short* __restrict__ A,
                                                  const unsigned short* __restrict__ BT,
                                                  float* __restrict__ Out) {
  const int MT = C_ / 128;   // 16
  const int NT = H_ / 128;   // 16
  int bid = blockIdx.x;
  int e = bid / (MT * NT);
  int r2 = bid % (MT * NT);
  int m0 = (r2 % MT) << 7;
  int n0 = (r2 / MT) << 7;

  const unsigned short* Ae = A + (size_t)e * C_ * I_;
  const unsigned short* Be = BT + (size_t)e * H_ * I_ + (size_t)n0 * I_;
  float* Oe = Out + (size_t)e * C_ * H_;

  __shared__ unsigned short lds[2 * 8192];  // A | B tiles

  int t = threadIdx.x, lane = t & 63, wave = t >> 6;
  int wr = (wave >> 1) << 6;
  int wc = (wave & 1) << 6;

  f32x4 acc[4][4] = {};

  int prow[4], pco[4], ldso[4];
#pragma unroll
  for (int it = 0; it < 4; ++it) {
    int p = it * 256 + t;
    prow[it] = p >> 3;
    int pc = p & 7;
    pco[it] = ((pc ^ (prow[it] & 7)) << 3);
    ldso[it] = (it * 256 + wave * 64) << 4;
  }

  for (int k0 = 0; k0 < I_; k0 += 64) {
    __syncthreads();
#pragma unroll
    for (int it = 0; it < 4; ++it) {
      gload16(Ae + (size_t)(m0 + prow[it]) * I_ + k0 + pco[it],
              (const char*)lds + ldso[it]);
      gload16(Be + (size_t)prow[it] * I_ + k0 + pco[it],
              (const char*)lds + 16384 + ldso[it]);
    }
    __syncthreads();
#pragma unroll
    for (int kk = 0; kk < 2; ++kk) {
      bf16x8 af[4], bf[4];
      int kg = (kk << 2) + (lane >> 4);
#pragma unroll
      for (int mi = 0; mi < 4; ++mi) {
        int row = wr + (mi << 4) + (lane & 15);
        int x = kg ^ (row & 7);
        af[mi] = *(const bf16x8*)((const char*)lds + row * 128 + (x << 4));
      }
#pragma unroll
      for (int ni = 0; ni < 4; ++ni) {
        int row = wc + (ni << 4) + (lane & 15);
        int x = kg ^ (row & 7);
        bf[ni] = *(const bf16x8*)((const char*)lds + 16384 + row * 128 + (x << 4));
      }
#pragma unroll
      for (int mi = 0; mi < 4; ++mi)
#pragma unroll
        for (int ni = 0; ni < 4; ++ni)
          acc[mi][ni] = __builtin_amdgcn_mfma_f32_16x16x32_bf16(af[mi], bf[ni], acc[mi][ni], 0, 0, 0);
    }
  }

  int rbase = m0 + wr + ((lane >> 4) << 2);
  int cbase = n0 + wc + (lane & 15);
#pragma unroll
  for (int mi = 0; mi < 4; ++mi)
#pragma unroll
    for (int ni = 0; ni < 4; ++ni)
#pragma unroll
      for (int r = 0; r < 4; ++r) {
        int row = rbase + (mi << 4) + r;
        int col = cbase + (ni << 4);
        Oe[(size_t)row * H_ + col] = acc[mi][ni][r];
      }
}

extern "C" void kernel_launch(void* const* d_in, const int* in_sizes, int n_in,
                              void* d_out, int out_size, void* d_ws, size_t ws_size,
                              hipStream_t stream) {
  const float* hidden = (const float*)d_in[0];
  const float* gateup = (const float*)d_in[1];
  const float* down = (const float*)d_in[2];
  float* out = (float*)d_out;

  unsigned short* ws = (unsigned short*)d_ws;
  unsigned short* hiddenB = ws;                                   // E*C*H bf16
  unsigned short* gateupT = hiddenB + (size_t)E_ * C_ * H_;       // E*2I*H bf16 (transposed)
  unsigned short* downT = gateupT + (size_t)E_ * N1_ * H_;        // E*H*I bf16 (transposed)
  unsigned short* actB = downT + (size_t)E_ * I_ * H_;            // E*C*I bf16

  cvt_bf16<<<2048, 256, 0, stream>>>(hidden, hiddenB, (E_ * C_ * H_) / 8);
  transpose_cvt<<<E_ * (H_ / 64) * (N1_ / 64), 256, 0, stream>>>(gateup, gateupT, H_, N1_);
  transpose_cvt<<<E_ * (I_ / 64) * (H_ / 64), 256, 0, stream>>>(down, downT, I_, H_);
  gemm1_glu<<<E_ * (C_ / 128) * (I_ / 128), 256, 0, stream>>>(hiddenB, gateupT, actB);
  gemm2_down<<<E_ * (C_ / 128) * (H_ / 128), 256, 0, stream>>>(actB, downT, out);
}

// Round 2
// 711.389 us; speedup vs baseline: 1.6996x; 1.6996x over previous
//
#include <hip/hip_runtime.h>
#include <hip/hip_bf16.h>
#include <stdint.h>

// Problem constants (fixed by setup_inputs)
#define E_ 8
#define C_ 2048
#define H_ 2048
#define I_ 2816
#define N1_ (2 * I_)   // 5632

typedef __attribute__((ext_vector_type(8))) short bf16x8;
typedef __attribute__((ext_vector_type(4))) float f32x4;

__device__ __forceinline__ unsigned short f2bf(float f) {
  union { float f; unsigned int u; } v; v.f = f;
  unsigned int u = v.u;
  unsigned int r = (u + 0x7FFFu + ((u >> 16) & 1u)) >> 16;  // RNE
  return (unsigned short)r;
}

__device__ __forceinline__ void gload16(const unsigned short* g, char* l) {
  __builtin_amdgcn_global_load_lds(
      (const __attribute__((address_space(1))) unsigned int*)g,
      (__attribute__((address_space(3))) unsigned int*)l, 16, 0, 0);
}

#define BARX()  do { asm volatile("" ::: "memory"); __builtin_amdgcn_s_barrier(); asm volatile("" ::: "memory"); } while (0)
#define LGKM0() asm volatile("s_waitcnt lgkmcnt(0)" ::: "memory")
#define VMC(n)  asm volatile("s_waitcnt vmcnt(" #n ")" ::: "memory")
#define PRIO(p) __builtin_amdgcn_s_setprio(p)

// ---------------- fp32 -> bf16 straight conversion (vectorized 8/thread) ----
__global__ __launch_bounds__(256) void cvt_bf16(const float* __restrict__ src,
                                                unsigned short* __restrict__ dst,
                                                int n8) {
  int idx = blockIdx.x * 256 + threadIdx.x;
  int stride = gridDim.x * 256;
  for (int i = idx; i < n8; i += stride) {
    const float4* s = (const float4*)(src + (size_t)i * 8);
    float4 a = s[0], b = s[1];
    uint4 o;
    o.x = (unsigned int)f2bf(a.x) | ((unsigned int)f2bf(a.y) << 16);
    o.y = (unsigned int)f2bf(a.z) | ((unsigned int)f2bf(a.w) << 16);
    o.z = (unsigned int)f2bf(b.x) | ((unsigned int)f2bf(b.y) << 16);
    o.w = (unsigned int)f2bf(b.z) | ((unsigned int)f2bf(b.w) << 16);
    *(uint4*)(dst + (size_t)i * 8) = o;
  }
}

// ---------------- fp32 [R][C] -> bf16 [C][R] per-expert transpose ----------
__global__ __launch_bounds__(256) void transpose_cvt(const float* __restrict__ src,
                                                     unsigned short* __restrict__ dst,
                                                     int R, int C) {
  int tilesC = C >> 6, tilesR = R >> 6;
  int tiles = tilesR * tilesC;
  int bid = blockIdx.x;
  int e = bid / tiles;
  int r2 = bid % tiles;
  int tr = r2 / tilesC, tc = r2 % tilesC;
  const float* s = src + (size_t)e * R * C;
  unsigned short* d = dst + (size_t)e * R * C;
  int r0 = tr << 6, c0 = tc << 6;

  __shared__ unsigned short lds[64 * 72];
  int t = threadIdx.x;
  int tx = t & 15, ty = t >> 4;
#pragma unroll
  for (int p = 0; p < 4; ++p) {
    int row = p * 16 + ty;
    float4 v = *(const float4*)(s + (size_t)(r0 + row) * C + c0 + tx * 4);
    int colb = tx * 4;
    lds[(colb + 0) * 72 + row] = f2bf(v.x);
    lds[(colb + 1) * 72 + row] = f2bf(v.y);
    lds[(colb + 2) * 72 + row] = f2bf(v.z);
    lds[(colb + 3) * 72 + row] = f2bf(v.w);
  }
  __syncthreads();
#pragma unroll
  for (int it = 0; it < 2; ++it) {
    int q = it * 256 + t;
    int nl = q >> 3, hc = q & 7;
    uint4 vv = *(const uint4*)(&lds[nl * 72 + hc * 8]);
    *(uint4*)(d + (size_t)(c0 + nl) * R + r0 + hc * 8) = vv;
  }
}

// ===================== GEMM1: 256x128 dual-B 8-phase GLU ====================
// A: [E][C][H] bf16 (k-major). BT: [E][2I][H] bf16 (n-major). act: [E][C][I] bf16.
// 8 waves (2Mx4N): wave output 128 rows x 32 cols x {gate, up}.
__global__ __launch_bounds__(512, 2) void gemm1_glu(const unsigned short* __restrict__ A,
                                                    const unsigned short* __restrict__ BT,
                                                    unsigned short* __restrict__ act) {
  constexpr int MT = C_ / 256;   // 8
  constexpr int NT = I_ / 128;   // 22
  constexpr int NK = H_ / 64;    // 32
  constexpr int NIT = NK / 2;    // 16
  const int nwg = E_ * MT * NT;  // 1408 (divisible by 8)
  int bid = blockIdx.x;
  int swz = (bid & 7) * (nwg >> 3) + (bid >> 3);
  int e = swz / (MT * NT);
  int r2 = swz % (MT * NT);
  int m0 = (r2 % MT) << 8;
  int n0 = (r2 / MT) << 7;

  const unsigned short* Ae = A + (size_t)e * C_ * H_ + (size_t)m0 * H_;
  const unsigned short* Ge = BT + (size_t)e * N1_ * H_ + (size_t)n0 * H_;
  const unsigned short* Ue = Ge + (size_t)I_ * H_;
  unsigned short* Ce = act + (size_t)e * C_ * I_;

  __shared__ char lds[131072];
  char* const A0b = lds;
  char* const A1b = lds + 32768;
  char* const B0b = lds + 65536;
  char* const B1b = lds + 98304;

  const int t = threadIdx.x, lane = t & 63, w = t >> 6;
  const int wr = (w >> 2) << 7;   // 0 / 128
  const int wc = (w & 3) << 5;    // 0,32,64,96

  const int la = lane & 15, kb = lane >> 4;
  const int ar = wr + la, s7a = ar & 7;
  const int br = wc + la, s7b = br & 7;

  // staging: q0 = t covers rows 0..63 of the half, q1 = t+512 rows 64..127
  const int sr0 = t >> 3, sc0 = t & 7;
  const int sof0 = sr0 * H_ + ((sc0 ^ (sr0 & 7)) << 3);
  const int sof1 = sof0 + 64 * H_;
  const int dof0 = t << 4, dof1 = (t << 4) + 8192;

#define STG1(gb, ko, lb) do { \
    gload16((gb) + (ko) + sof0, (lb) + dof0); \
    gload16((gb) + (ko) + sof1, (lb) + dof1); } while (0)

#define RDA(buf, m4) \
  _Pragma("unroll") for (int mi = 0; mi < 4; ++mi) \
  _Pragma("unroll") for (int kk = 0; kk < 2; ++kk) \
    fa[(m4) + mi][kk] = *(const bf16x8*)((buf) + (ar + ((m4) + mi) * 16) * 128 + ((((kk << 2) | kb) ^ s7a) << 4));

#define RDBG(buf, dst, ro) \
  _Pragma("unroll") for (int ni = 0; ni < 2; ++ni) \
  _Pragma("unroll") for (int kk = 0; kk < 2; ++kk) \
    dst[ni][kk] = *(const bf16x8*)((buf) + ((ro) + br + ni * 16) * 128 + ((((kk << 2) | kb) ^ s7b) << 4));

#define MMG(accA, m4, bfr) \
  _Pragma("unroll") for (int mi = 0; mi < 4; ++mi) \
  _Pragma("unroll") for (int ni = 0; ni < 2; ++ni) \
  _Pragma("unroll") for (int kk = 0; kk < 2; ++kk) \
    accA[(m4) + mi][ni] = __builtin_amdgcn_mfma_f32_16x16x32_bf16(fa[(m4) + mi][kk], bfr[ni][kk], accA[(m4) + mi][ni], 0, 0, 0);

  f32x4 accg[8][2] = {};
  f32x4 accu[8][2] = {};
  bf16x8 fa[8][2], fg[2][2], fu[2][2];

  // prologue: tile0 {Ah0,Ah1,Bg,Bu}, tile1 {Ah0,Ah1}
  STG1(Ae, 0, A0b); STG1(Ae + 128 * H_, 0, A0b + 16384);
  STG1(Ge, 0, B0b); STG1(Ue, 0, B0b + 16384);
  STG1(Ae, 64, A1b); STG1(Ae + 128 * H_, 64, A1b + 16384);
  VMC(4); BARX();

  for (int i = 0; i < NIT; ++i) {
    const int kc = i * 128;
    const bool nx = (i + 1 < NIT);
    // ph1: read a(mh0)+bg from buf0; stage (T+1).Bg -> B1
    RDA(A0b, 0); RDBG(B0b, fg, 0);
    STG1(Ge, kc + 64, B1b);
    BARX(); LGKM0();
    PRIO(1); MMG(accg, 0, fg); PRIO(0); BARX();
    // ph2: read a(mh1)+bu; stage (T+1).Bu -> B1
    RDA(A0b, 4); RDBG(B0b, fu, 128);
    STG1(Ue, kc + 64, B1b + 16384);
    BARX(); LGKM0();
    PRIO(1); MMG(accu, 0, fu); PRIO(0); BARX();
    // ph3: stage (T+2).Ah0 -> A0 (buf0 reads done at end ph2)
    if (nx) STG1(Ae, kc + 128, A0b);
    BARX();
    PRIO(1); MMG(accg, 4, fg); PRIO(0); BARX();
    // ph4: stage (T+2).Ah1; vmcnt ensures tile T+1 fully landed
    if (nx) { STG1(Ae + 128 * H_, kc + 128, A0b + 16384); VMC(4); } else { VMC(0); }
    BARX();
    PRIO(1); MMG(accu, 4, fu); PRIO(0); BARX();
    // ph5: read buf1 a(mh0)+bg; stage (T+2).Bg -> B0
    RDA(A1b, 0); RDBG(B1b, fg, 0);
    if (nx) STG1(Ge, kc + 128, B0b);
    BARX(); LGKM0();
    PRIO(1); MMG(accg, 0, fg); PRIO(0); BARX();
    // ph6: read buf1 a(mh1)+bu; stage (T+2).Bu -> B0
    RDA(A1b, 4); RDBG(B1b, fu, 128);
    if (nx) STG1(Ue, kc + 128, B0b + 16384);
    BARX(); LGKM0();
    PRIO(1); MMG(accu, 0, fu); PRIO(0); BARX();
    // ph7: stage (T+3).Ah0 -> A1 (buf1 reads done at end ph6)
    if (nx) STG1(Ae, kc + 192, A1b);
    BARX();
    PRIO(1); MMG(accg, 4, fg); PRIO(0); BARX();
    // ph8: stage (T+3).Ah1; vmcnt ensures tile T+2 fully landed
    if (nx) { STG1(Ae + 128 * H_, kc + 192, A1b + 16384); VMC(4); }
    BARX();
    PRIO(1); MMG(accu, 4, fu); PRIO(0); BARX();
  }

  // Epilogue: act = silu(g) * u. C/D layout: col=lane&15, row=(lane>>4)*4+reg
  const int rb = m0 + wr + (kb << 2);
  const int cb = n0 + wc + la;
#pragma unroll
  for (int mi = 0; mi < 8; ++mi)
#pragma unroll
    for (int ni = 0; ni < 2; ++ni)
#pragma unroll
      for (int r = 0; r < 4; ++r) {
        float g = accg[mi][ni][r], u = accu[mi][ni][r];
        float s = g / (1.0f + __expf(-g));
        Ce[(size_t)(rb + mi * 16 + r) * I_ + (cb + ni * 16)] = f2bf(s * u);
      }
#undef STG1
}

// ===================== GEMM2: 256x256 8-phase, fp32 out =====================
// A: [E][C][I] bf16. BT: [E][H][I] bf16 (n-major). Out: [E][C][H] fp32.
__global__ __launch_bounds__(512, 2) void gemm2_down(const unsigned short* __restrict__ A,
                                                     const unsigned short* __restrict__ BT,
                                                     float* __restrict__ Out) {
  constexpr int MT = C_ / 256;   // 8
  constexpr int NT = H_ / 256;   // 8
  constexpr int NK = I_ / 64;    // 44
  constexpr int NIT = NK / 2;    // 22
  const int nwg = E_ * MT * NT;  // 512
  int bid = blockIdx.x;
  int swz = (bid & 7) * (nwg >> 3) + (bid >> 3);
  int e = swz / (MT * NT);
  int r2 = swz % (MT * NT);
  int m0 = (r2 % MT) << 8;
  int n0 = (r2 / MT) << 8;

  const unsigned short* Ae = A + (size_t)e * C_ * I_ + (size_t)m0 * I_;
  const unsigned short* Be = BT + (size_t)e * H_ * I_ + (size_t)n0 * I_;
  float* Oe = Out + (size_t)e * C_ * H_;

  __shared__ char lds[131072];
  char* const A0b = lds;
  char* const A1b = lds + 32768;
  char* const B0b = lds + 65536;
  char* const B1b = lds + 98304;

  const int t = threadIdx.x, lane = t & 63, w = t >> 6;
  const int wr = (w >> 2) << 7;   // 0 / 128
  const int wc = (w & 3) << 6;    // 0,64,128,192

  const int la = lane & 15, kb = lane >> 4;
  const int ar = wr + la, s7a = ar & 7;
  const int br = wc + la, s7b = br & 7;

  const int sr0 = t >> 3, sc0 = t & 7;
  const int sof0 = sr0 * I_ + ((sc0 ^ (sr0 & 7)) << 3);
  const int sof1 = sof0 + 64 * I_;
  const int dof0 = t << 4, dof1 = (t << 4) + 8192;

#define STG2(gb, ko, lb) do { \
    gload16((gb) + (ko) + sof0, (lb) + dof0); \
    gload16((gb) + (ko) + sof1, (lb) + dof1); } while (0)

#define RDB4(buf, n2) \
  _Pragma("unroll") for (int ni = 0; ni < 2; ++ni) \
  _Pragma("unroll") for (int kk = 0; kk < 2; ++kk) \
    fb[(n2) + ni][kk] = *(const bf16x8*)((buf) + (br + ((n2) + ni) * 16) * 128 + ((((kk << 2) | kb) ^ s7b) << 4));

#define MM4(m4, n2) \
  _Pragma("unroll") for (int mi = 0; mi < 4; ++mi) \
  _Pragma("unroll") for (int ni = 0; ni < 2; ++ni) \
  _Pragma("unroll") for (int kk = 0; kk < 2; ++kk) \
    acc[(m4) + mi][(n2) + ni] = __builtin_amdgcn_mfma_f32_16x16x32_bf16(fa[(m4) + mi][kk], fb[(n2) + ni][kk], acc[(m4) + mi][(n2) + ni], 0, 0, 0);

  f32x4 acc[8][4] = {};
  bf16x8 fa[8][2], fb[4][2];

  // prologue
  STG2(Ae, 0, A0b); STG2(Ae + 128 * I_, 0, A0b + 16384);
  STG2(Be, 0, B0b); STG2(Be + 128 * I_, 0, B0b + 16384);
  STG2(Ae, 64, A1b); STG2(Ae + 128 * I_, 64, A1b + 16384);
  VMC(4); BARX();

  for (int i = 0; i < NIT; ++i) {
    const int kc = i * 128;
    const bool nx = (i + 1 < NIT);
    // ph1
    RDA(A0b, 0); RDB4(B0b, 0);
    STG2(Be, kc + 64, B1b);
    BARX(); LGKM0();
    PRIO(1); MM4(0, 0); PRIO(0); BARX();
    // ph2
    RDA(A0b, 4); RDB4(B0b, 2);
    STG2(Be + 128 * I_, kc + 64, B1b + 16384);
    BARX(); LGKM0();
    PRIO(1); MM4(0, 2); PRIO(0); BARX();
    // ph3
    if (nx) STG2(Ae, kc + 128, A0b);
    BARX();
    PRIO(1); MM4(4, 0); PRIO(0); BARX();
    // ph4
    if (nx) { STG2(Ae + 128 * I_, kc + 128, A0b + 16384); VMC(4); } else { VMC(0); }
    BARX();
    PRIO(1); MM4(4, 2); PRIO(0); BARX();
    // ph5
    RDA(A1b, 0); RDB4(B1b, 0);
    if (nx) STG2(Be, kc + 128, B0b);
    BARX(); LGKM0();
    PRIO(1); MM4(0, 0); PRIO(0); BARX();
    // ph6
    RDA(A1b, 4); RDB4(B1b, 2);
    if (nx) STG2(Be + 128 * I_, kc + 128, B0b + 16384);
    BARX(); LGKM0();
    PRIO(1); MM4(0, 2); PRIO(0); BARX();
    // ph7
    if (nx) STG2(Ae, kc + 192, A1b);
    BARX();
    PRIO(1); MM4(4, 0); PRIO(0); BARX();
    // ph8
    if (nx) { STG2(Ae + 128 * I_, kc + 192, A1b + 16384); VMC(4); }
    BARX();
    PRIO(1); MM4(4, 2); PRIO(0); BARX();
  }

  const int rb = m0 + wr + (kb << 2);
  const int cb = n0 + wc + la;
#pragma unroll
  for (int mi = 0; mi < 8; ++mi)
#pragma unroll
    for (int ni = 0; ni < 4; ++ni)
#pragma unroll
      for (int r = 0; r < 4; ++r)
        Oe[(size_t)(rb + mi * 16 + r) * H_ + (cb + ni * 16)] = acc[mi][ni][r];
#undef STG2
}

extern "C" void kernel_launch(void* const* d_in, const int* in_sizes, int n_in,
                              void* d_out, int out_size, void* d_ws, size_t ws_size,
                              hipStream_t stream) {
  const float* hidden = (const float*)d_in[0];
  const float* gateup = (const float*)d_in[1];
  const float* down = (const float*)d_in[2];
  float* out = (float*)d_out;

  unsigned short* ws = (unsigned short*)d_ws;
  unsigned short* hiddenB = ws;                                   // E*C*H bf16
  unsigned short* gateupT = hiddenB + (size_t)E_ * C_ * H_;       // E*2I*H bf16 (transposed)
  unsigned short* downT = gateupT + (size_t)E_ * N1_ * H_;        // E*H*I bf16 (transposed)
  unsigned short* actB = downT + (size_t)E_ * I_ * H_;            // E*C*I bf16

  cvt_bf16<<<2048, 256, 0, stream>>>(hidden, hiddenB, (E_ * C_ * H_) / 8);
  transpose_cvt<<<E_ * (H_ / 64) * (N1_ / 64), 256, 0, stream>>>(gateup, gateupT, H_, N1_);
  transpose_cvt<<<E_ * (I_ / 64) * (H_ / 64), 256, 0, stream>>>(down, downT, I_, H_);
  gemm1_glu<<<E_ * (C_ / 256) * (I_ / 128), 512, 0, stream>>>(hiddenB, gateupT, actB);
  gemm2_down<<<E_ * (C_ / 256) * (H_ / 256), 512, 0, stream>>>(actB, downT, out);
}